// Round 8
// baseline (767.370 us; speedup 1.0000x reference)
//
#include <hip/hip_runtime.h>
#include <math.h>

#define L_SEQ 2048
#define NCH   64
#define LCH   32

using bf16x8 = __attribute__((ext_vector_type(8))) short;
using u16x8  = __attribute__((ext_vector_type(8))) unsigned short;
using f32x4  = __attribute__((ext_vector_type(4))) float;

__device__ __forceinline__ float sigmoidf_(float x){ return 1.f/(1.f+__expf(-x)); }
__device__ __forceinline__ unsigned short hi16(float a){ return (unsigned short)(__float_as_uint(a)>>16); }
__device__ __forceinline__ unsigned short lo16(float a){
    const float h = __uint_as_float(__float_as_uint(a) & 0xffff0000u);
    return (unsigned short)(__float_as_uint(a - h)>>16);
}

#define GLD_LDS16(g, l) __builtin_amdgcn_global_load_lds( \
    (const __attribute__((address_space(1))) void*)(g),   \
    (__attribute__((address_space(3))) void*)(l), 16, 0, 0)

// ---------------------------------------------------------------------------
// Packed tile image (per BM-row panel, per 32-col K-tile): byte pos*16 holds
// 8 bf16: r_loc = pos>>3, s = pos&7, val = s ^ (r_loc&7), plane p = val>>2
// (0 hi / 1 lo), k-group g = val&3, elements X[row][kb*32 + g*8 .. +7].
// A linear global_load_lds stream then lands so LDS addr =
// r*128 + ((p*4+g)^(r&7))*16 — the r3-HW-verified fragment layout.
// ---------------------------------------------------------------------------
__global__ __launch_bounds__(256)
void pack_k(const float* __restrict__ src, int lda, int Rvalid, int flip,
            int tsh, int ksh, unsigned short* __restrict__ dst, int total)
{
    const int g0 = blockIdx.x*256 + threadIdx.x;
    if (g0 >= total) return;
    const int tile = g0 >> tsh;
    const int pos  = g0 & ((1<<tsh)-1);
    const int r_loc = pos>>3, s = pos&7;
    const int kb = tile & ((1<<ksh)-1);
    const int rb = tile >> ksh;
    const int r  = (rb << (tsh-3)) + r_loc;
    const int val = s ^ (r_loc & 7);
    const int p = val>>2, g = val&3;
    u16x8 o;
    if (r < Rvalid){
        int sr = flip ? ((r & ~(L_SEQ-1)) | ((L_SEQ-1)-(r&(L_SEQ-1)))) : r;
        const float* rp = src + (size_t)sr*lda + kb*32 + g*8;
#pragma unroll
        for (int u=0;u<8;u++) o[u] = p ? lo16(rp[u]) : hi16(rp[u]);
    } else {
#pragma unroll
        for (int u=0;u<8;u++) o[u] = 0;
    }
    *(u16x8*)(dst + (size_t)g0*8) = o;
}

// ---------------------------------------------------------------------------
// Packed-operand GEMM: C[M,N] = epi( A @ W^T + bias ), split-bf16 (3 MFMA).
// BM in {64,128}, BN=128, BK=32, 256 thr = 4 waves (2x2), dbuf LDS,
// global_load_lds staging, r3-verified fragment/epilogue layout.
// ---------------------------------------------------------------------------
template<int EPI, int BM>
__global__ __launch_bounds__(256, 2)
void pgemm(const char* __restrict__ Ap, const char* __restrict__ Wp,
           const float* __restrict__ bias, float* __restrict__ C,
           int ldc, int N, int K)
{
    constexpr int TA = BM*128, TB = 16384, BUF = TA+TB, MWF = BM/32;
    __shared__ __attribute__((aligned(128))) char lds[2*BUF];
    const int tid = threadIdx.x;
    const int ntk = K>>5;
    const int rb = blockIdx.y, cb = blockIdx.x;
    const char* apan = Ap + (size_t)rb*ntk*TA;
    const char* wpan = Wp + (size_t)cb*ntk*TB;

    const int lane = tid&63, wid = tid>>6;
    const int wm = wid>>1, wn = wid&1;
    const int fr = lane&15, kh = lane>>4;
    const int shi = (kh ^ (fr&7))<<4;
    int aoff[MWF], boff[4];
#pragma unroll
    for (int mf=0;mf<MWF;mf++) aoff[mf] = (wm*(BM/2)+mf*16+fr)*128 + shi;
#pragma unroll
    for (int nf=0;nf<4;nf++)  boff[nf] = (wn*64+nf*16+fr)*128 + shi;

    f32x4 acc[MWF][4];
#pragma unroll
    for (int i=0;i<MWF;i++)
#pragma unroll
        for (int j=0;j<4;j++) acc[i][j] = (f32x4){0.f,0.f,0.f,0.f};

    auto stage = [&](int buf, int kt){
        const char* as_ = apan + (size_t)kt*TA + tid*16;
        const char* ws_ = wpan + (size_t)kt*TB + tid*16;
        char* ld = lds + buf*BUF + tid*16;
#pragma unroll
        for (int i=0;i<MWF;i++) GLD_LDS16(as_ + i*4096, ld + i*4096);
#pragma unroll
        for (int i=0;i<4;i++)   GLD_LDS16(ws_ + i*4096, ld + TA + i*4096);
    };

    stage(0, 0);
    __syncthreads();                       // drains vmcnt: tile 0 resident
    for (int kt=0; kt<ntk; ++kt){
        const int cur = kt&1;
        if (kt+1 < ntk) stage(cur^1, kt+1);     // prefetch hides under MFMA
        const char* Ab = lds + cur*BUF;
        const char* Bb = Ab + TA;
        bf16x8 ah[MWF], al[MWF], bh[4], bl[4];
#pragma unroll
        for (int mf=0;mf<MWF;mf++){
            ah[mf] = *(const bf16x8*)(Ab + aoff[mf]);
            al[mf] = *(const bf16x8*)(Ab + (aoff[mf]^64));
        }
#pragma unroll
        for (int nf=0;nf<4;nf++){
            bh[nf] = *(const bf16x8*)(Bb + boff[nf]);
            bl[nf] = *(const bf16x8*)(Bb + (boff[nf]^64));
        }
#pragma unroll
        for (int mf=0;mf<MWF;mf++)
#pragma unroll
            for (int nf=0;nf<4;nf++){
                acc[mf][nf] = __builtin_amdgcn_mfma_f32_16x16x32_bf16(ah[mf], bh[nf], acc[mf][nf], 0,0,0);
                acc[mf][nf] = __builtin_amdgcn_mfma_f32_16x16x32_bf16(ah[mf], bl[nf], acc[mf][nf], 0,0,0);
                acc[mf][nf] = __builtin_amdgcn_mfma_f32_16x16x32_bf16(al[mf], bh[nf], acc[mf][nf], 0,0,0);
            }
        __syncthreads();                   // drains prefetch + LDS reuse
    }

    // epilogue: D layout col=lane&15, row=(lane>>4)*4+reg  [r3/m89-verified]
#pragma unroll
    for (int mf=0; mf<MWF; mf++){
        const int grow = rb*BM + wm*(BM/2) + mf*16 + kh*4;
#pragma unroll
        for (int nf=0; nf<4; nf++){
            const int gcol = cb*128 + wn*64 + nf*16 + fr;
            if (gcol < N){
                const float bv = (EPI>=1) ? bias[gcol] : 0.f;
#pragma unroll
                for (int j=0;j<4;j++){
                    float v = acc[mf][nf][j] + bv;
                    if (EPI==2) v = fmaxf(v, 0.f);
                    if (EPI==3) v = fmaxf(v,0.f) + log1pf(__expf(-fabsf(v)));
                    C[(size_t)(grow+j)*ldc + gcol] = v;
                }
            }
        }
    }
}

// ---------------------------------------------------------------------------
// Causal depthwise conv1d (k=4, left pad 3) + SiLU; writes xi fp32 AND the
// BM=64-packed image for the xproj GEMM (K=1024 -> 32 k-tiles of 8192 B).
// ---------------------------------------------------------------------------
__global__ __launch_bounds__(256)
void conv_silu_pack(const float* __restrict__ xz, const float* __restrict__ cw,
                    const float* __restrict__ cb, float* __restrict__ xi,
                    char* __restrict__ xi_pk)
{
    const int tid = threadIdx.x;
    const int j  = tid & 127;            // 8-channel group
    const int rl = tid >> 7;
    const int row = blockIdx.x*2 + rl;   // 0..4095
    const int l = row & (L_SEQ-1);
    const int d0 = j*8;
    float acc[8];
#pragma unroll
    for (int c=0;c<8;c++) acc[c] = cb[d0+c];
    float wt[8][4];
#pragma unroll
    for (int c=0;c<8;c++){
        const float4 w4 = *(const float4*)(cw + (d0+c)*4);
        wt[c][0]=w4.x; wt[c][1]=w4.y; wt[c][2]=w4.z; wt[c][3]=w4.w;
    }
    const float* base = xz + (size_t)row*2048 + d0;
#pragma unroll
    for (int k=0;k<4;k++){
        if (l-3+k >= 0){
            const float* xp = base + (k-3)*2048;
#pragma unroll
            for (int c=0;c<8;c++) acc[c] = fmaf(wt[c][k], xp[c], acc[c]);
        }
    }
    float v[8];
#pragma unroll
    for (int c=0;c<8;c++) v[c] = acc[c] * sigmoidf_(acc[c]);
    *(float4*)(xi + (size_t)row*1024 + d0)     = make_float4(v[0],v[1],v[2],v[3]);
    *(float4*)(xi + (size_t)row*1024 + d0 + 4) = make_float4(v[4],v[5],v[6],v[7]);
    const int g = (d0>>3)&3, kb = d0>>5;
    const size_t tbase = ((size_t)(row>>6)*32 + kb)*8192
                       + ((row&63)>>5)*4096 + (row&31)*128;
    const int s_hi = g ^ (row&7);
    u16x8 h, lo;
#pragma unroll
    for (int c=0;c<8;c++){ h[c] = hi16(v[c]); lo[c] = lo16(v[c]); }
    *(u16x8*)(xi_pk + tbase + s_hi*16)        = h;
    *(u16x8*)(xi_pk + ((tbase + s_hi*16)^64)) = lo;
}

// ---------------------------------------------------------------------------
// Scan
// ---------------------------------------------------------------------------
__global__ __launch_bounds__(256)
void scan_part1(const float* __restrict__ delta, const float* __restrict__ xi,
                const float* __restrict__ dbc, const float* __restrict__ A_log,
                float* __restrict__ Aprod, float* __restrict__ Bsum)
{
    const int d = blockIdx.x*256 + threadIdx.x;
    const int c = blockIdx.y;
    const int b = blockIdx.z;
    __shared__ float Bm[LCH][16];
    const int r0 = b*L_SEQ + c*LCH;
    for (int idx = threadIdx.x; idx < LCH*16; idx += 256){
        const int i = idx >> 4, n = idx & 15;
        Bm[i][n] = dbc[(size_t)(r0+i)*64 + 32 + n];
    }
    __syncthreads();
    float Ad[16];
#pragma unroll
    for (int n=0;n<16;n++) Ad[n] = -__expf(A_log[d*16+n]);
    float ap[16], bs[16];
#pragma unroll
    for (int n=0;n<16;n++){ ap[n]=1.f; bs[n]=0.f; }
    for (int i=0;i<LCH;i++){
        const size_t r = (size_t)(r0 + i);
        const float dl = delta[r*1024 + d];
        const float xv = xi[r*1024 + d];
        const float dx = dl * xv;
#pragma unroll
        for (int n=0;n<16;n++){
            const float da = __expf(dl * Ad[n]);
            bs[n] = fmaf(da, bs[n], dx * Bm[i][n]);
            ap[n] *= da;
        }
    }
    const size_t o = ((size_t)((b*NCH + c)*1024) + d) * 16;
#pragma unroll
    for (int n=0;n<16;n+=4){
        *(float4*)(Aprod + o + n) = make_float4(ap[n],ap[n+1],ap[n+2],ap[n+3]);
        *(float4*)(Bsum  + o + n) = make_float4(bs[n],bs[n+1],bs[n+2],bs[n+3]);
    }
}

// NOTE: hinit ALIASES Aprod in the caller's workspace plan — parameters are
// deliberately NOT __restrict__. Reads Aprod[o]/Bsum[o] strictly before
// writing hinit[o] (same thread, same index) -> well-defined.
__global__ __launch_bounds__(256)
void scan_part2(const float* Aprod, const float* Bsum, float* hinit)
{
    const int g = blockIdx.x*256 + threadIdx.x;
    const int n = g & 15; const int d = (g>>4) & 1023; const int b = g >> 14;
    float h = 0.f;
    for (int c=0;c<NCH;c++){
        const size_t o = ((size_t)((b*NCH + c)*1024) + d)*16 + n;
        const float a = Aprod[o];
        const float bb = Bsum[o];
        hinit[o] = h;
        h = fmaf(a, h, bb);
    }
}

__global__ __launch_bounds__(256)
void scan_part3(const float* __restrict__ delta, const float* __restrict__ xi,
                const float* __restrict__ dbc, const float* __restrict__ xz,
                const float* __restrict__ A_log, const float* __restrict__ Dp,
                const float* __restrict__ hinit, float* __restrict__ y)
{
    const int d = blockIdx.x*256 + threadIdx.x;
    const int c = blockIdx.y;
    const int b = blockIdx.z;
    __shared__ float Bm[LCH][16], Cm[LCH][16];
    const int r0 = b*L_SEQ + c*LCH;
    for (int idx = threadIdx.x; idx < LCH*16; idx += 256){
        const int i = idx >> 4, n = idx & 15;
        const float* rowp = dbc + (size_t)(r0+i)*64;
        Bm[i][n] = rowp[32+n];
        Cm[i][n] = rowp[48+n];
    }
    __syncthreads();
    float Ad[16];
#pragma unroll
    for (int n=0;n<16;n++) Ad[n] = -__expf(A_log[d*16+n]);
    float h[16];
    const size_t ho = ((size_t)((b*NCH + c)*1024) + d)*16;
#pragma unroll
    for (int n=0;n<16;n++) h[n] = hinit[ho+n];
    const float Dd = Dp[d];
    for (int i=0;i<LCH;i++){
        const size_t r = (size_t)(r0 + i);
        const float dl = delta[r*1024 + d];
        const float xv = xi[r*1024 + d];
        const float dx = dl * xv;
        float yv = 0.f;
#pragma unroll
        for (int n=0;n<16;n++){
            const float da = __expf(dl * Ad[n]);
            h[n] = fmaf(da, h[n], dx * Bm[i][n]);
            yv = fmaf(h[n], Cm[i][n], yv);
        }
        yv = fmaf(Dd, xv, yv);
        const float zv = xz[r*2048 + 1024 + d];
        yv *= zv * sigmoidf_(zv);
        y[r*1024 + d] = yv;
    }
}

// ---------------------------------------------------------------------------
// out = [addafter +] LN( a(flip?) + res ) * w + b; optional BM=128 packed out
// (K=512 -> 16 k-tiles of 16384 B) for feeding the next GEMM.
// ---------------------------------------------------------------------------
__global__ __launch_bounds__(128)
void ln_k(const float* __restrict__ a, int flipA, const float* __restrict__ res,
          const float* __restrict__ w, const float* __restrict__ bb,
          const float* __restrict__ addafter, float* __restrict__ out,
          char* __restrict__ pk)
{
    const int row = blockIdx.x;
    const int tid = threadIdx.x;
    int ar = row;
    if (flipA) ar = (row & ~(L_SEQ-1)) | ((L_SEQ-1) - (row & (L_SEQ-1)));
    const int col = tid*4;
    const float4 av = *(const float4*)(a + (size_t)ar*512 + col);
    const float4 rv = *(const float4*)(res + (size_t)row*512 + col);
    const float v0=av.x+rv.x, v1=av.y+rv.y, v2=av.z+rv.z, v3=av.w+rv.w;
    float s  = v0+v1+v2+v3;
    float sq = v0*v0+v1*v1+v2*v2+v3*v3;
#pragma unroll
    for (int off=32; off>0; off>>=1){
        s  += __shfl_xor(s, off);
        sq += __shfl_xor(sq, off);
    }
    __shared__ float red[4];
    if ((tid & 63) == 0){ red[(tid>>6)*2] = s; red[(tid>>6)*2+1] = sq; }
    __syncthreads();
    s = red[0] + red[2]; sq = red[1] + red[3];
    const float mean = s * (1.f/512.f);
    const float var  = sq * (1.f/512.f) - mean*mean;
    const float rstd = rsqrtf(var + 1e-5f);
    const float4 wv = *(const float4*)(w + col);
    const float4 bv = *(const float4*)(bb + col);
    float o0 = (v0-mean)*rstd*wv.x + bv.x;
    float o1 = (v1-mean)*rstd*wv.y + bv.y;
    float o2 = (v2-mean)*rstd*wv.z + bv.z;
    float o3 = (v3-mean)*rstd*wv.w + bv.w;
    if (pk){   // pack BEFORE addafter (pk consumers use the LN output)
        const int g = (col>>3)&3, kb = col>>5, h = (col>>2)&1;
        const size_t tbase = ((size_t)(row>>7)*16 + kb)*16384
                           + ((row&127)>>5)*4096 + (row&31)*128;
        const int s_hi = g ^ (row&7);
        ushort4 hh, ll;
        hh.x=hi16(o0); hh.y=hi16(o1); hh.z=hi16(o2); hh.w=hi16(o3);
        ll.x=lo16(o0); ll.y=lo16(o1); ll.z=lo16(o2); ll.w=lo16(o3);
        *(ushort4*)(pk + tbase + s_hi*16 + h*8)        = hh;
        *(ushort4*)(pk + ((tbase + s_hi*16)^64) + h*8) = ll;
    }
    if (addafter){
        const float4 xv = *(const float4*)(addafter + (size_t)row*512 + col);
        o0 += xv.x; o1 += xv.y; o2 += xv.z; o3 += xv.w;
    }
    *(float4*)(out + (size_t)row*512 + col) = make_float4(o0,o1,o2,o3);
}

// ---------------------------------------------------------------------------
extern "C" void kernel_launch(void* const* d_in, const int* in_sizes, int n_in,
                              void* d_out, int out_size, void* d_ws, size_t ws_size,
                              hipStream_t stream)
{
    const float* x = (const float*)d_in[0];
    struct DirP { const float *in_w,*conv_w,*conv_b,*xproj_w,*dt_w,*dt_b,*A_log,*D,*out_w; };
    DirP dp[2];
    for (int p=0;p<2;p++){
        const int b = 1 + p*9;
        dp[p].in_w    = (const float*)d_in[b+0];
        dp[p].conv_w  = (const float*)d_in[b+1];
        dp[p].conv_b  = (const float*)d_in[b+2];
        dp[p].xproj_w = (const float*)d_in[b+3];
        dp[p].dt_w    = (const float*)d_in[b+4];
        dp[p].dt_b    = (const float*)d_in[b+5];
        dp[p].A_log   = (const float*)d_in[b+6];
        dp[p].D       = (const float*)d_in[b+7];
        dp[p].out_w   = (const float*)d_in[b+8];
    }
    const float* lnw[4]; const float* lnb[4];
    for (int i=0;i<4;i++){ lnw[i]=(const float*)d_in[19+2*i]; lnb[i]=(const float*)d_in[20+2*i]; }
    const float* f1w1=(const float*)d_in[27]; const float* f1b1=(const float*)d_in[28];
    const float* f1w2=(const float*)d_in[29]; const float* f1b2=(const float*)d_in[30];
    const float* f2w1=(const float*)d_in[31]; const float* f2b1=(const float*)d_in[32];
    const float* f2w2=(const float*)d_in[33]; const float* f2b2=(const float*)d_in[34];

    // ---- workspace plan: 157.5 MB total (proven envelope was 161 MB) ----
    char* ws = (char*)d_ws;
    size_t off = 0;
    auto alloc = [&](size_t bytes){ char* p = ws + off; off = (off + bytes + 255) & ~(size_t)255; return p; };
    const size_t M = 4096;
    float* xz    = (float*)alloc(M*2048*4);            // 32 MB
    float* xi    = (float*)alloc(M*1024*4);            // 16 MB
    float* dbc   = (float*)alloc(M*64*4);              //  1 MB
    float* dfh   = (float*)alloc(M*1024*4);            // 16 MB  delta, then ffh
    float* yb    = (float*)alloc(M*1024*4);            // 16 MB
    float* Aprod = (float*)alloc((size_t)2*NCH*1024*16*4);  // 8 MB (hinit aliases)
    float* Bsum  = (float*)alloc((size_t)2*NCH*1024*16*4);  // 8 MB
    float* mamba = (float*)alloc(M*512*4);             //  8 MB  mamba, then ffo
    float* xf1   = (float*)alloc(M*512*4);             //  8 MB  xf1 (p0) / xb1 (p1)
    float* xf2   = (float*)alloc(M*512*4);             //  8 MB  persists p0->p1
    char*  xpk   = alloc(M*512*4);                     //  8 MB  x-pack / xf1_pk
    char*  apk64 = alloc(M*1024*4);                    // 16 MB  xi/yb/ffh pack
    char*  dbc_pk= alloc(M*32*4);                      // 0.5 MB
    char*  xf2_pk= alloc(M*512*4);                     //  8 MB  persists p0->p1
    char*  wpk   = alloc((size_t)2048*512*4);          //  4 MB  JIT weight packs
    float* hinit = Aprod;                              // alias (scan_part2 non-restrict)
    float* delta = dfh;
    float* ffh   = dfh;
    float* ffo   = mamba;
    float* xb1   = xf1;
    char*  xf1_pk= xpk;
    (void)ws_size; (void)in_sizes; (void)n_in; (void)out_size;

    const dim3 blk(256);
    auto pkg = [](int total){ return dim3((unsigned)((total+255)/256)); };

    for (int p=0;p<2;p++){
        const DirP& d = dp[p];
        // pack x (flip for backward) + in_w, then in_proj -> xz
        pack_k<<<pkg(524288), blk, 0, stream>>>(x, 512, 4096, p, 10, 4, (unsigned short*)xpk, 524288);
        pack_k<<<pkg(262144), blk, 0, stream>>>(d.in_w, 512, 2048, 0, 10, 4, (unsigned short*)wpk, 262144);
        pgemm<0,128><<<dim3(16,32), blk, 0, stream>>>(xpk, wpk, nullptr, xz, 2048, 2048, 512);
        // conv + silu -> xi fp32 + packed (BM=64, K=1024)
        conv_silu_pack<<<dim3(2048), blk, 0, stream>>>(xz, d.conv_w, d.conv_b, xi, apk64);
        // x_proj -> dbc
        pack_k<<<pkg(32768), blk, 0, stream>>>(d.xproj_w, 1024, 64, 0, 10, 5, (unsigned short*)wpk, 32768);
        pgemm<0,64><<<dim3(1,64), blk, 0, stream>>>(apk64, wpk, nullptr, dbc, 64, 64, 1024);
        // dt_proj + softplus -> delta
        pack_k<<<pkg(32768), blk, 0, stream>>>(dbc, 64, 4096, 0, 10, 0, (unsigned short*)dbc_pk, 32768);
        pack_k<<<pkg(8192),  blk, 0, stream>>>(d.dt_w, 32, 1024, 0, 10, 0, (unsigned short*)wpk, 8192);
        pgemm<3,128><<<dim3(8,32), blk, 0, stream>>>(dbc_pk, wpk, d.dt_b, delta, 1024, 1024, 32);
        // chunked associative scan
        scan_part1<<<dim3(4,NCH,2), blk, 0, stream>>>(delta, xi, dbc, d.A_log, Aprod, Bsum);
        scan_part2<<<dim3(128), blk, 0, stream>>>(Aprod, Bsum, hinit);
        scan_part3<<<dim3(4,NCH,2), blk, 0, stream>>>(delta, xi, dbc, xz, d.A_log, d.D, hinit, yb);
        // out_proj -> mamba
        pack_k<<<pkg(1048576), blk, 0, stream>>>(yb, 1024, 4096, 0, 9, 5, (unsigned short*)apk64, 1048576);
        pack_k<<<pkg(131072),  blk, 0, stream>>>(d.out_w, 1024, 512, 0, 10, 5, (unsigned short*)wpk, 131072);
        pgemm<0,64><<<dim3(4,64), blk, 0, stream>>>(apk64, wpk, nullptr, mamba, 512, 512, 1024);
        if (p==0){
            ln_k<<<4096,128,0,stream>>>(mamba, 0, x, lnw[0], lnb[0], nullptr, xf1, xf1_pk);
            pack_k<<<pkg(131072), blk, 0, stream>>>(f1w1, 512, 1024, 0, 10, 4, (unsigned short*)wpk, 131072);
            pgemm<2,128><<<dim3(8,32), blk,0,stream>>>(xf1_pk, wpk, f1b1, ffh, 1024, 1024, 512);
            pack_k<<<pkg(1048576), blk, 0, stream>>>(ffh, 1024, 4096, 0, 9, 5, (unsigned short*)apk64, 1048576);
            pack_k<<<pkg(131072),  blk, 0, stream>>>(f1w2, 1024, 512, 0, 10, 5, (unsigned short*)wpk, 131072);
            pgemm<1,64><<<dim3(4,64), blk,0,stream>>>(apk64, wpk, f1b2, ffo, 512, 512, 1024);
            ln_k<<<4096,128,0,stream>>>(ffo, 0, xf1, lnw[1], lnb[1], nullptr, xf2, xf2_pk);
        } else {
            ln_k<<<4096,128,0,stream>>>(mamba, 1, x, lnw[2], lnb[2], nullptr, xb1, nullptr);
            // NOTE: faithful to reference bug — ffn2 consumes x_f2, not x_b
            pack_k<<<pkg(131072), blk, 0, stream>>>(f2w1, 512, 1024, 0, 10, 4, (unsigned short*)wpk, 131072);
            pgemm<2,128><<<dim3(8,32), blk,0,stream>>>(xf2_pk, wpk, f2b1, ffh, 1024, 1024, 512);
            pack_k<<<pkg(1048576), blk, 0, stream>>>(ffh, 1024, 4096, 0, 9, 5, (unsigned short*)apk64, 1048576);
            pack_k<<<pkg(131072),  blk, 0, stream>>>(f2w2, 1024, 512, 0, 10, 5, (unsigned short*)wpk, 131072);
            pgemm<1,64><<<dim3(4,64), blk,0,stream>>>(apk64, wpk, f2b2, ffo, 512, 512, 1024);
            // x_b2 = LN(ffo + x_b1); final out = x_f2 + x_b2 (fused)
            ln_k<<<4096,128,0,stream>>>(ffo, 0, xb1, lnw[3], lnb[3], xf2, (float*)d_out, nullptr);
        }
    }
}

// Round 9
// 674.308 us; speedup vs baseline: 1.1380x; 1.1380x over previous
//
#include <hip/hip_runtime.h>
#include <math.h>

#define L_SEQ 2048
#define NCH   64
#define LCH   32

using bf16x8 = __attribute__((ext_vector_type(8))) short;
using u16x8  = __attribute__((ext_vector_type(8))) unsigned short;
using f32x4  = __attribute__((ext_vector_type(4))) float;

__device__ __forceinline__ float sigmoidf_(float x){ return 1.f/(1.f+__expf(-x)); }
__device__ __forceinline__ unsigned short hi16(float a){ return (unsigned short)(__float_as_uint(a)>>16); }
__device__ __forceinline__ unsigned short lo16(float a){
    const float h = __uint_as_float(__float_as_uint(a) & 0xffff0000u);
    return (unsigned short)(__float_as_uint(a - h)>>16);
}

#define GLD_LDS16(g, l) __builtin_amdgcn_global_load_lds( \
    (const __attribute__((address_space(1))) void*)(g),   \
    (__attribute__((address_space(3))) void*)(l), 16, 0, 0)

// Packed image algebra (HW-validated in r8): for element (r,c) of an [M,K]
// operand with BMO-row panels and 32-col k-tiles:
//   tile base = ((r/BMO)*ntk2 + (c>>5)) * (BMO*128) + (r%BMO)*128
//   slot(plane p) = ((p*4 + ((c>>3)&3)) ^ (r&7)),  byte = slot*16 + (c&7)*2
// A linear global_load_lds stream then lands hi at LDS slot, lo at ^64.

// ---------------------------------------------------------------------------
// One-launch pack of all 12 weight tensors (descriptor table, tsh=10).
// ---------------------------------------------------------------------------
struct PkD { const float* src; unsigned short* dst; int lda, R, ksh, start; };
struct PkTab { PkD d[12]; int total; };

__global__ __launch_bounds__(256)
void pack_w_all(PkTab t)
{
    const int gid = blockIdx.x*256 + threadIdx.x;
    if (gid >= t.total) return;
    int i = 0;
#pragma unroll
    for (int k=1;k<12;k++) if (gid >= t.d[k].start) i = k;
    const PkD D = t.d[i];
    const int g0 = gid - D.start;
    const int tile = g0 >> 10, pos = g0 & 1023;
    const int r_loc = pos>>3, s = pos&7;
    const int kb = tile & ((1<<D.ksh)-1);
    const int rb = tile >> D.ksh;
    const int r  = rb*128 + r_loc;
    const int val = s ^ (r_loc & 7);
    const int p = val>>2, g = val&3;
    u16x8 o;
    if (r < D.R){
        const float* rp = D.src + (size_t)r*D.lda + kb*32 + g*8;
#pragma unroll
        for (int u=0;u<8;u++) o[u] = p ? lo16(rp[u]) : hi16(rp[u]);
    } else {
#pragma unroll
        for (int u=0;u<8;u++) o[u] = 0;
    }
    *(u16x8*)(D.dst + (size_t)g0*8) = o;
}

// ---------------------------------------------------------------------------
// Pack activation x into BOTH direction images (fwd + seq-flipped) in one
// read. BM=128 panels, K=512 -> 16 k-tiles.
// ---------------------------------------------------------------------------
__global__ __launch_bounds__(256)
void xpack_both(const float* __restrict__ x,
                unsigned short* __restrict__ f, unsigned short* __restrict__ b)
{
    const int g0 = blockIdx.x*256 + threadIdx.x;    // 524288 total
    const int tile = g0 >> 10, pos = g0 & 1023;
    const int r_loc = pos>>3, s = pos&7;
    const int kb = tile & 15, rb = tile >> 4;
    const int r  = rb*128 + r_loc;
    const int val = s ^ (r_loc & 7);
    const int p = val>>2, g = val&3;
    const float* rp = x + (size_t)r*512 + kb*32 + g*8;
    u16x8 o;
#pragma unroll
    for (int u=0;u<8;u++) o[u] = p ? lo16(rp[u]) : hi16(rp[u]);
    *(u16x8*)(f + (size_t)g0*8) = o;
    // same data lands at the flipped row's position in the backward image
    const int rr = (r & ~(L_SEQ-1)) | ((L_SEQ-1) - (r & (L_SEQ-1)));
    const int rr_loc = rr & 127;
    const int tile_b = (rr>>7)*16 + kb;
    const int s_b = (p*4+g) ^ (rr_loc & 7);
    *(u16x8*)(b + ((size_t)tile_b*1024 + rr_loc*8 + s_b)*8) = o;
}

// ---------------------------------------------------------------------------
// Packed-operand GEMM: C = epi( A @ W^T + bias ), split-bf16 (3 MFMA).
// POUT: 0 = fp32 C only; 1 = packed-only output (BMO=64 image, ntk2=N/32);
//       2 = fp32 C + packed image of cols<32 (BMO=128, ntk2=1).
// TAG distinguishes call-sites in rocprof.
// ---------------------------------------------------------------------------
template<int EPI, int BM, int POUT, int TAG>
__global__ __launch_bounds__(256, 2)
void pgemm(const char* __restrict__ Ap, const char* __restrict__ Wp,
           const float* __restrict__ bias, float* __restrict__ C,
           char* __restrict__ pkout, int ldc, int N, int K)
{
    constexpr int TA = BM*128, TB = 16384, BUF = TA+TB, MWF = BM/32;
    __shared__ __attribute__((aligned(128))) char lds[2*BUF];
    const int tid = threadIdx.x;
    const int ntk = K>>5;
    const int rb = blockIdx.y, cb = blockIdx.x;
    const char* apan = Ap + (size_t)rb*ntk*TA;
    const char* wpan = Wp + (size_t)cb*ntk*TB;

    const int lane = tid&63, wid = tid>>6;
    const int wm = wid>>1, wn = wid&1;
    const int fr = lane&15, kh = lane>>4;
    const int shi = (kh ^ (fr&7))<<4;
    int aoff[MWF], boff[4];
#pragma unroll
    for (int mf=0;mf<MWF;mf++) aoff[mf] = (wm*(BM/2)+mf*16+fr)*128 + shi;
#pragma unroll
    for (int nf=0;nf<4;nf++)  boff[nf] = (wn*64+nf*16+fr)*128 + shi;

    f32x4 acc[MWF][4];
#pragma unroll
    for (int i=0;i<MWF;i++)
#pragma unroll
        for (int j=0;j<4;j++) acc[i][j] = (f32x4){0.f,0.f,0.f,0.f};

    auto stage = [&](int buf, int kt){
        const char* as_ = apan + (size_t)kt*TA + tid*16;
        const char* ws_ = wpan + (size_t)kt*TB + tid*16;
        char* ld = lds + buf*BUF + tid*16;
#pragma unroll
        for (int i=0;i<MWF;i++) GLD_LDS16(as_ + i*4096, ld + i*4096);
#pragma unroll
        for (int i=0;i<4;i++)   GLD_LDS16(ws_ + i*4096, ld + TA + i*4096);
    };

    stage(0, 0);
    __syncthreads();
    for (int kt=0; kt<ntk; ++kt){
        const int cur = kt&1;
        if (kt+1 < ntk) stage(cur^1, kt+1);
        const char* Ab = lds + cur*BUF;
        const char* Bb = Ab + TA;
        bf16x8 ah[MWF], al[MWF], bh[4], bl[4];
#pragma unroll
        for (int mf=0;mf<MWF;mf++){
            ah[mf] = *(const bf16x8*)(Ab + aoff[mf]);
            al[mf] = *(const bf16x8*)(Ab + (aoff[mf]^64));
        }
#pragma unroll
        for (int nf=0;nf<4;nf++){
            bh[nf] = *(const bf16x8*)(Bb + boff[nf]);
            bl[nf] = *(const bf16x8*)(Bb + (boff[nf]^64));
        }
#pragma unroll
        for (int mf=0;mf<MWF;mf++)
#pragma unroll
            for (int nf=0;nf<4;nf++){
                acc[mf][nf] = __builtin_amdgcn_mfma_f32_16x16x32_bf16(ah[mf], bh[nf], acc[mf][nf], 0,0,0);
                acc[mf][nf] = __builtin_amdgcn_mfma_f32_16x16x32_bf16(ah[mf], bl[nf], acc[mf][nf], 0,0,0);
                acc[mf][nf] = __builtin_amdgcn_mfma_f32_16x16x32_bf16(al[mf], bh[nf], acc[mf][nf], 0,0,0);
            }
        __syncthreads();
    }

    // packed store helper (r8-validated algebra)
    auto pstore = [&](int r, int c, float v){
        constexpr int BMO = (POUT==1) ? 64 : 128;
        const int ntk2 = (POUT==1) ? (N>>5) : 1;
        const size_t tb = ((size_t)(r/BMO)*ntk2 + (c>>5))*(size_t)(BMO*128)
                        + (size_t)(r & (BMO-1))*128;
        const int gq = (c>>3)&3, rx = r&7, c2 = (c&7)*2;
        *(unsigned short*)(pkout + tb + (size_t)((gq^rx))*16 + c2)     = hi16(v);
        *(unsigned short*)(pkout + tb + (size_t)(((4|gq)^rx))*16 + c2) = lo16(v);
    };

#pragma unroll
    for (int mf=0; mf<MWF; mf++){
        const int grow = rb*BM + wm*(BM/2) + mf*16 + kh*4;
#pragma unroll
        for (int nf=0; nf<4; nf++){
            const int gcol = cb*128 + wn*64 + nf*16 + fr;
            if (gcol < N){
                const float bv = (EPI>=1) ? bias[gcol] : 0.f;
#pragma unroll
                for (int j=0;j<4;j++){
                    float v = acc[mf][nf][j] + bv;
                    if (EPI==2) v = fmaxf(v, 0.f);
                    if (EPI==3) v = fmaxf(v,0.f) + log1pf(__expf(-fabsf(v)));
                    const int r = grow + j;
                    if (POUT != 1) C[(size_t)r*ldc + gcol] = v;
                    if (POUT == 1) pstore(r, gcol, v);
                    if (POUT == 2 && gcol < 32) pstore(r, gcol, v);
                }
            }
        }
    }
}

// ---------------------------------------------------------------------------
// Causal depthwise conv1d (k=4, left pad 3) + SiLU -> xi fp32 + packed image
// (BM=64, K=1024). Byte-identical to the r8-validated kernel.
// ---------------------------------------------------------------------------
__global__ __launch_bounds__(256)
void conv_silu_pack(const float* __restrict__ xz, const float* __restrict__ cw,
                    const float* __restrict__ cb, float* __restrict__ xi,
                    char* __restrict__ xi_pk)
{
    const int tid = threadIdx.x;
    const int j  = tid & 127;
    const int rl = tid >> 7;
    const int row = blockIdx.x*2 + rl;
    const int l = row & (L_SEQ-1);
    const int d0 = j*8;
    float acc[8];
#pragma unroll
    for (int c=0;c<8;c++) acc[c] = cb[d0+c];
    float wt[8][4];
#pragma unroll
    for (int c=0;c<8;c++){
        const float4 w4 = *(const float4*)(cw + (d0+c)*4);
        wt[c][0]=w4.x; wt[c][1]=w4.y; wt[c][2]=w4.z; wt[c][3]=w4.w;
    }
    const float* base = xz + (size_t)row*2048 + d0;
#pragma unroll
    for (int k=0;k<4;k++){
        if (l-3+k >= 0){
            const float* xp = base + (k-3)*2048;
#pragma unroll
            for (int c=0;c<8;c++) acc[c] = fmaf(wt[c][k], xp[c], acc[c]);
        }
    }
    float v[8];
#pragma unroll
    for (int c=0;c<8;c++) v[c] = acc[c] * sigmoidf_(acc[c]);
    *(float4*)(xi + (size_t)row*1024 + d0)     = make_float4(v[0],v[1],v[2],v[3]);
    *(float4*)(xi + (size_t)row*1024 + d0 + 4) = make_float4(v[4],v[5],v[6],v[7]);
    const int g = (d0>>3)&3, kb = d0>>5;
    const size_t tbase = ((size_t)(row>>6)*32 + kb)*8192
                       + ((row&63)>>5)*4096 + (row&31)*128;
    const int s_hi = g ^ (row&7);
    u16x8 h, lo;
#pragma unroll
    for (int c=0;c<8;c++){ h[c] = hi16(v[c]); lo[c] = lo16(v[c]); }
    *(u16x8*)(xi_pk + tbase + s_hi*16)        = h;
    *(u16x8*)(xi_pk + ((tbase + s_hi*16)^64)) = lo;
}

// ---------------------------------------------------------------------------
// Scan
// ---------------------------------------------------------------------------
__global__ __launch_bounds__(256)
void scan_part1(const float* __restrict__ delta, const float* __restrict__ xi,
                const float* __restrict__ dbc, const float* __restrict__ A_log,
                float* __restrict__ Aprod, float* __restrict__ Bsum)
{
    const int d = blockIdx.x*256 + threadIdx.x;
    const int c = blockIdx.y;
    const int b = blockIdx.z;
    __shared__ float Bm[LCH][16];
    const int r0 = b*L_SEQ + c*LCH;
    for (int idx = threadIdx.x; idx < LCH*16; idx += 256){
        const int i = idx >> 4, n = idx & 15;
        Bm[i][n] = dbc[(size_t)(r0+i)*64 + 32 + n];
    }
    __syncthreads();
    float Ad[16];
#pragma unroll
    for (int n=0;n<16;n++) Ad[n] = -__expf(A_log[d*16+n]);
    float ap[16], bs[16];
#pragma unroll
    for (int n=0;n<16;n++){ ap[n]=1.f; bs[n]=0.f; }
    for (int i=0;i<LCH;i++){
        const size_t r = (size_t)(r0 + i);
        const float dl = delta[r*1024 + d];
        const float xv = xi[r*1024 + d];
        const float dx = dl * xv;
#pragma unroll
        for (int n=0;n<16;n++){
            const float da = __expf(dl * Ad[n]);
            bs[n] = fmaf(da, bs[n], dx * Bm[i][n]);
            ap[n] *= da;
        }
    }
    const size_t o = ((size_t)((b*NCH + c)*1024) + d) * 16;
#pragma unroll
    for (int n=0;n<16;n+=4){
        *(float4*)(Aprod + o + n) = make_float4(ap[n],ap[n+1],ap[n+2],ap[n+3]);
        *(float4*)(Bsum  + o + n) = make_float4(bs[n],bs[n+1],bs[n+2],bs[n+3]);
    }
}

// hinit ALIASES Aprod in the workspace plan — deliberately NOT __restrict__.
__global__ __launch_bounds__(256)
void scan_part2(const float* Aprod, const float* Bsum, float* hinit)
{
    const int g = blockIdx.x*256 + threadIdx.x;
    const int n = g & 15; const int d = (g>>4) & 1023; const int b = g >> 14;
    float h = 0.f;
    for (int c=0;c<NCH;c++){
        const size_t o = ((size_t)((b*NCH + c)*1024) + d)*16 + n;
        const float a = Aprod[o];
        const float bb = Bsum[o];
        hinit[o] = h;
        h = fmaf(a, h, bb);
    }
}

// Pass 3: y written DIRECTLY as packed image (BM=64, K=1024) for out_proj.
__global__ __launch_bounds__(256)
void scan_part3(const float* __restrict__ delta, const float* __restrict__ xi,
                const float* __restrict__ dbc, const float* __restrict__ xz,
                const float* __restrict__ A_log, const float* __restrict__ Dp,
                const float* __restrict__ hinit, char* __restrict__ ypk)
{
    const int d = blockIdx.x*256 + threadIdx.x;
    const int c = blockIdx.y;
    const int b = blockIdx.z;
    __shared__ float Bm[LCH][16], Cm[LCH][16];
    const int r0 = b*L_SEQ + c*LCH;
    for (int idx = threadIdx.x; idx < LCH*16; idx += 256){
        const int i = idx >> 4, n = idx & 15;
        const float* rowp = dbc + (size_t)(r0+i)*64;
        Bm[i][n] = rowp[32+n];
        Cm[i][n] = rowp[48+n];
    }
    __syncthreads();
    float Ad[16];
#pragma unroll
    for (int n=0;n<16;n++) Ad[n] = -__expf(A_log[d*16+n]);
    float h[16];
    const size_t ho = ((size_t)((b*NCH + c)*1024) + d)*16;
#pragma unroll
    for (int n=0;n<16;n++) h[n] = hinit[ho+n];
    const float Dd = Dp[d];
    const int gq = (d>>3)&3, c2 = (d&7)*2;
    for (int i=0;i<LCH;i++){
        const int r = r0 + i;
        const float dl = delta[(size_t)r*1024 + d];
        const float xv = xi[(size_t)r*1024 + d];
        const float dx = dl * xv;
        float yv = 0.f;
#pragma unroll
        for (int n=0;n<16;n++){
            const float da = __expf(dl * Ad[n]);
            h[n] = fmaf(da, h[n], dx * Bm[i][n]);
            yv = fmaf(h[n], Cm[i][n], yv);
        }
        yv = fmaf(Dd, xv, yv);
        const float zv = xz[(size_t)r*2048 + 1024 + d];
        yv *= zv * sigmoidf_(zv);
        const size_t tb = ((size_t)(r>>6)*32 + (d>>5))*8192 + (size_t)(r&63)*128;
        const int rx = r&7;
        *(unsigned short*)(ypk + tb + (size_t)((gq^rx))*16 + c2)     = hi16(yv);
        *(unsigned short*)(ypk + tb + (size_t)(((4|gq)^rx))*16 + c2) = lo16(yv);
    }
}

// ---------------------------------------------------------------------------
// out = [addafter +] LN( a(flip?) + res ) * w + b; optional BM=128 packed out.
// ---------------------------------------------------------------------------
__global__ __launch_bounds__(128)
void ln_k(const float* __restrict__ a, int flipA, const float* __restrict__ res,
          const float* __restrict__ w, const float* __restrict__ bb,
          const float* __restrict__ addafter, float* __restrict__ out,
          char* __restrict__ pk)
{
    const int row = blockIdx.x;
    const int tid = threadIdx.x;
    int ar = row;
    if (flipA) ar = (row & ~(L_SEQ-1)) | ((L_SEQ-1) - (row & (L_SEQ-1)));
    const int col = tid*4;
    const float4 av = *(const float4*)(a + (size_t)ar*512 + col);
    const float4 rv = *(const float4*)(res + (size_t)row*512 + col);
    const float v0=av.x+rv.x, v1=av.y+rv.y, v2=av.z+rv.z, v3=av.w+rv.w;
    float s  = v0+v1+v2+v3;
    float sq = v0*v0+v1*v1+v2*v2+v3*v3;
#pragma unroll
    for (int off=32; off>0; off>>=1){
        s  += __shfl_xor(s, off);
        sq += __shfl_xor(sq, off);
    }
    __shared__ float red[4];
    if ((tid & 63) == 0){ red[(tid>>6)*2] = s; red[(tid>>6)*2+1] = sq; }
    __syncthreads();
    s = red[0] + red[2]; sq = red[1] + red[3];
    const float mean = s * (1.f/512.f);
    const float var  = sq * (1.f/512.f) - mean*mean;
    const float rstd = rsqrtf(var + 1e-5f);
    const float4 wv = *(const float4*)(w + col);
    const float4 bv = *(const float4*)(bb + col);
    float o0 = (v0-mean)*rstd*wv.x + bv.x;
    float o1 = (v1-mean)*rstd*wv.y + bv.y;
    float o2 = (v2-mean)*rstd*wv.z + bv.z;
    float o3 = (v3-mean)*rstd*wv.w + bv.w;
    if (pk){
        const int g = (col>>3)&3, kb = col>>5, h = (col>>2)&1;
        const size_t tbase = ((size_t)(row>>7)*16 + kb)*16384
                           + ((row&127)>>5)*4096 + (row&31)*128;
        const int s_hi = g ^ (row&7);
        ushort4 hh, ll;
        hh.x=hi16(o0); hh.y=hi16(o1); hh.z=hi16(o2); hh.w=hi16(o3);
        ll.x=lo16(o0); ll.y=lo16(o1); ll.z=lo16(o2); ll.w=lo16(o3);
        *(ushort4*)(pk + tbase + s_hi*16 + h*8)        = hh;
        *(ushort4*)(pk + ((tbase + s_hi*16)^64) + h*8) = ll;
    }
    if (addafter){
        const float4 xv = *(const float4*)(addafter + (size_t)row*512 + col);
        o0 += xv.x; o1 += xv.y; o2 += xv.z; o3 += xv.w;
    }
    *(float4*)(out + (size_t)row*512 + col) = make_float4(o0,o1,o2,o3);
}

// ---------------------------------------------------------------------------
extern "C" void kernel_launch(void* const* d_in, const int* in_sizes, int n_in,
                              void* d_out, int out_size, void* d_ws, size_t ws_size,
                              hipStream_t stream)
{
    const float* x = (const float*)d_in[0];
    struct DirP { const float *in_w,*conv_w,*conv_b,*xproj_w,*dt_w,*dt_b,*A_log,*D,*out_w; };
    DirP dp[2];
    for (int p=0;p<2;p++){
        const int b = 1 + p*9;
        dp[p].in_w    = (const float*)d_in[b+0];
        dp[p].conv_w  = (const float*)d_in[b+1];
        dp[p].conv_b  = (const float*)d_in[b+2];
        dp[p].xproj_w = (const float*)d_in[b+3];
        dp[p].dt_w    = (const float*)d_in[b+4];
        dp[p].dt_b    = (const float*)d_in[b+5];
        dp[p].A_log   = (const float*)d_in[b+6];
        dp[p].D       = (const float*)d_in[b+7];
        dp[p].out_w   = (const float*)d_in[b+8];
    }
    const float* lnw[4]; const float* lnb[4];
    for (int i=0;i<4;i++){ lnw[i]=(const float*)d_in[19+2*i]; lnb[i]=(const float*)d_in[20+2*i]; }
    const float* f1w1=(const float*)d_in[27]; const float* f1b1=(const float*)d_in[28];
    const float* f1w2=(const float*)d_in[29]; const float* f1b2=(const float*)d_in[30];
    const float* f2w1=(const float*)d_in[31]; const float* f2b1=(const float*)d_in[32];
    const float* f2w2=(const float*)d_in[33]; const float* f2b2=(const float*)d_in[34];

    // ---- workspace plan: ~166 MB (ws_size evidence: 256 MiB fill) ----
    char* ws = (char*)d_ws;
    size_t off = 0;
    auto alloc = [&](size_t bytes){ char* p = ws + off; off = (off + bytes + 255) & ~(size_t)255; return p; };
    const size_t M = 4096;
    float* xz    = (float*)alloc(M*2048*4);
    float* xi    = (float*)alloc(M*1024*4);
    float* dbc   = (float*)alloc(M*64*4);
    float* delta = (float*)alloc(M*1024*4);
    float* Aprod = (float*)alloc((size_t)2*NCH*1024*16*4);   // hinit aliases
    float* Bsum  = (float*)alloc((size_t)2*NCH*1024*16*4);
    float* mamba = (float*)alloc(M*512*4);                   // also ffo
    float* xf1   = (float*)alloc(M*512*4);                   // also xb1
    float* xf2   = (float*)alloc(M*512*4);
    char*  xpk_f = alloc(M*512*4);                           // also xf1_pk
    char*  xpk_b = alloc(M*512*4);
    char*  apk64 = alloc(M*1024*4);                          // xi_pk / yb_pk / ffh_pk
    char*  dbc_pk= alloc(M*32*4);
    char*  xf2_pk= alloc(M*512*4);
    unsigned short* w_in[2];  unsigned short* w_xp[2];
    unsigned short* w_dt[2];  unsigned short* w_out[2];
    for (int p=0;p<2;p++){
        w_in[p]  = (unsigned short*)alloc((size_t)262144*16);
        w_xp[p]  = (unsigned short*)alloc((size_t)32768*16);
        w_dt[p]  = (unsigned short*)alloc((size_t)8192*16);
        w_out[p] = (unsigned short*)alloc((size_t)131072*16);
    }
    unsigned short* w_f1w1 = (unsigned short*)alloc((size_t)131072*16);
    unsigned short* w_f1w2 = (unsigned short*)alloc((size_t)131072*16);
    unsigned short* w_f2w1 = (unsigned short*)alloc((size_t)131072*16);
    unsigned short* w_f2w2 = (unsigned short*)alloc((size_t)131072*16);
    float* hinit = Aprod;
    float* ffo   = mamba;
    float* xb1   = xf1;
    char*  xf1_pk= xpk_f;
    (void)ws_size; (void)in_sizes; (void)n_in; (void)out_size;

    const dim3 blk(256);

    // ---- one-launch weight pack ----
    PkTab tab;
    int cur = 0; int ti = 0;
    auto addw = [&](const float* src, unsigned short* dst, int lda, int R, int ksh, int tot){
        tab.d[ti++] = PkD{src, dst, lda, R, ksh, cur}; cur += tot;
    };
    for (int p=0;p<2;p++){
        addw(dp[p].in_w,    w_in[p],  512,  2048, 4, 262144);
        addw(dp[p].xproj_w, w_xp[p],  1024, 64,   5, 32768);
        addw(dp[p].dt_w,    w_dt[p],  32,   1024, 0, 8192);
        addw(dp[p].out_w,   w_out[p], 1024, 512,  5, 131072);
    }
    addw(f1w1, w_f1w1, 512,  1024, 4, 131072);
    addw(f1w2, w_f1w2, 1024, 512,  5, 131072);
    addw(f2w1, w_f2w1, 512,  1024, 4, 131072);
    addw(f2w2, w_f2w2, 1024, 512,  5, 131072);
    tab.total = cur;                                  // 1,392,640
    pack_w_all<<<dim3((tab.total+255)/256), blk, 0, stream>>>(tab);
    xpack_both<<<dim3(2048), blk, 0, stream>>>(x, (unsigned short*)xpk_f, (unsigned short*)xpk_b);

    for (int p=0;p<2;p++){
        const DirP& d = dp[p];
        const char* xpk = (p==0) ? xpk_f : xpk_b;
        // in_proj -> xz
        pgemm<0,128,0,0><<<dim3(16,32), blk, 0, stream>>>(xpk, (char*)w_in[p], nullptr, xz, nullptr, 2048, 2048, 512);
        // conv + silu -> xi fp32 + packed
        conv_silu_pack<<<dim3(2048), blk, 0, stream>>>(xz, d.conv_w, d.conv_b, xi, apk64);
        // x_proj -> dbc fp32 + dbc[:, :32] packed
        pgemm<0,64,2,1><<<dim3(1,64), blk, 0, stream>>>(apk64, (char*)w_xp[p], nullptr, dbc, dbc_pk, 64, 64, 1024);
        // dt_proj + softplus -> delta
        pgemm<3,128,0,2><<<dim3(8,32), blk, 0, stream>>>(dbc_pk, (char*)w_dt[p], d.dt_b, delta, nullptr, 1024, 1024, 32);
        // chunked associative scan; part3 writes yb packed directly
        scan_part1<<<dim3(4,NCH,2), blk, 0, stream>>>(delta, xi, dbc, d.A_log, Aprod, Bsum);
        scan_part2<<<dim3(128), blk, 0, stream>>>(Aprod, Bsum, hinit);
        scan_part3<<<dim3(4,NCH,2), blk, 0, stream>>>(delta, xi, dbc, xz, d.A_log, d.D, hinit, apk64);
        // out_proj -> mamba
        pgemm<0,64,0,3><<<dim3(4,64), blk, 0, stream>>>(apk64, (char*)w_out[p], nullptr, mamba, nullptr, 512, 512, 1024);
        if (p==0){
            ln_k<<<4096,128,0,stream>>>(mamba, 0, x, lnw[0], lnb[0], nullptr, xf1, xf1_pk);
            // ffn1: packed-only output (ffh fp32 never needed)
            pgemm<2,128,1,4><<<dim3(8,32), blk,0,stream>>>(xf1_pk, (char*)w_f1w1, f1b1, nullptr, apk64, 1024, 1024, 512);
            pgemm<1,64,0,5><<<dim3(4,64), blk,0,stream>>>(apk64, (char*)w_f1w2, f1b2, ffo, nullptr, 512, 512, 1024);
            ln_k<<<4096,128,0,stream>>>(ffo, 0, xf1, lnw[1], lnb[1], nullptr, xf2, xf2_pk);
        } else {
            ln_k<<<4096,128,0,stream>>>(mamba, 1, x, lnw[2], lnb[2], nullptr, xb1, nullptr);
            // NOTE: faithful to reference bug — ffn2 consumes x_f2, not x_b
            pgemm<2,128,1,4><<<dim3(8,32), blk,0,stream>>>(xf2_pk, (char*)w_f2w1, f2b1, nullptr, apk64, 1024, 1024, 512);
            pgemm<1,64,0,5><<<dim3(4,64), blk,0,stream>>>(apk64, (char*)w_f2w2, f2b2, ffo, nullptr, 512, 512, 1024);
            // x_b2 = LN(ffo + x_b1); final out = x_f2 + x_b2 (fused)
            ln_k<<<4096,128,0,stream>>>(ffo, 0, xb1, lnw[3], lnb[3], xf2, (float*)d_out, nullptr);
        }
    }
}

// Round 13
// 643.228 us; speedup vs baseline: 1.1930x; 1.0483x over previous
//
#include <hip/hip_runtime.h>
#include <math.h>

#define L_SEQ 2048
#define NCH   64
#define LCH   32

using bf16x8 = __attribute__((ext_vector_type(8))) short;
using u16x8  = __attribute__((ext_vector_type(8))) unsigned short;
using f32x4  = __attribute__((ext_vector_type(4))) float;

__device__ __forceinline__ float sigmoidf_(float x){ return 1.f/(1.f+__expf(-x)); }
__device__ __forceinline__ unsigned short hi16(float a){ return (unsigned short)(__float_as_uint(a)>>16); }
__device__ __forceinline__ unsigned short lo16(float a){
    const float h = __uint_as_float(__float_as_uint(a) & 0xffff0000u);
    return (unsigned short)(__float_as_uint(a - h)>>16);
}

#define GLD_LDS16(g, l) __builtin_amdgcn_global_load_lds( \
    (const __attribute__((address_space(1))) void*)(g),   \
    (__attribute__((address_space(3))) void*)(l), 16, 0, 0)

// Packed image algebra (HW-validated r8): element (r,c) of [M,K], BMO-row
// panels, 32-col k-tiles:
//   tile base = ((r/BMO)*ntk2 + (c>>5)) * (BMO*128) + (r%BMO)*128
//   slot(plane p) = ((p*4 + ((c>>3)&3)) ^ (r&7)),  byte = slot*16 + (c&7)*2

// ---------------------------------------------------------------------------
// One-launch pack of all 12 weight tensors.
// ---------------------------------------------------------------------------
struct PkD { const float* src; unsigned short* dst; int lda, R, ksh, start; };
struct PkTab { PkD d[12]; int total; };

__global__ __launch_bounds__(256)
void pack_w_all(PkTab t)
{
    const int gid = blockIdx.x*256 + threadIdx.x;
    if (gid >= t.total) return;
    int i = 0;
#pragma unroll
    for (int k=1;k<12;k++) if (gid >= t.d[k].start) i = k;
    const PkD D = t.d[i];
    const int g0 = gid - D.start;
    const int tile = g0 >> 10, pos = g0 & 1023;
    const int r_loc = pos>>3, s = pos&7;
    const int kb = tile & ((1<<D.ksh)-1);
    const int rb = tile >> D.ksh;
    const int r  = rb*128 + r_loc;
    const int val = s ^ (r_loc & 7);
    const int p = val>>2, g = val&3;
    u16x8 o;
    if (r < D.R){
        const float* rp = D.src + (size_t)r*D.lda + kb*32 + g*8;
#pragma unroll
        for (int u=0;u<8;u++) o[u] = p ? lo16(rp[u]) : hi16(rp[u]);
    } else {
#pragma unroll
        for (int u=0;u<8;u++) o[u] = 0;
    }
    *(u16x8*)(D.dst + (size_t)g0*8) = o;
}

// ---------------------------------------------------------------------------
// Pack activation x into BOTH direction images (fwd + flipped) in one read.
// ---------------------------------------------------------------------------
__global__ __launch_bounds__(256)
void xpack_both(const float* __restrict__ x,
                unsigned short* __restrict__ f, unsigned short* __restrict__ b)
{
    const int g0 = blockIdx.x*256 + threadIdx.x;    // 524288 total
    const int tile = g0 >> 10, pos = g0 & 1023;
    const int r_loc = pos>>3, s = pos&7;
    const int kb = tile & 15, rb = tile >> 4;
    const int r  = rb*128 + r_loc;
    const int val = s ^ (r_loc & 7);
    const int p = val>>2, g = val&3;
    const float* rp = x + (size_t)r*512 + kb*32 + g*8;
    u16x8 o;
#pragma unroll
    for (int u=0;u<8;u++) o[u] = p ? lo16(rp[u]) : hi16(rp[u]);
    *(u16x8*)(f + (size_t)g0*8) = o;
    const int rr = (r & ~(L_SEQ-1)) | ((L_SEQ-1) - (r & (L_SEQ-1)));
    const int rr_loc = rr & 127;
    const int tile_b = (rr>>7)*16 + kb;
    const int s_b = (p*4+g) ^ (rr_loc & 7);
    *(u16x8*)(b + ((size_t)tile_b*1024 + rr_loc*8 + s_b)*8) = o;
}

// ---------------------------------------------------------------------------
// Packed-operand GEMM, split-bf16 (3 MFMA). Optional split-K via gridDim.z
// (partial slabs at C + z*zstride; epi applied by the reduce kernel then).
// XCD-chunked block remap (bijective, requires nwg%8==0 — all our grids).
// ---------------------------------------------------------------------------
template<int EPI, int BM, int TAG>
__global__ __launch_bounds__(256, 2)
void pgemm(const char* __restrict__ Ap, const char* __restrict__ Wp,
           const float* __restrict__ bias, float* __restrict__ C,
           size_t zstride, int ldc, int N, int K)
{
    constexpr int TA = BM*128, TB = 16384, BUF = TA+TB, MWF = BM/32;
    __shared__ __attribute__((aligned(128))) char lds[2*BUF];
    const int tid = threadIdx.x;
    const int ntk_all = K>>5;
    const int ntk = ntk_all / gridDim.z;
    const int kt0 = blockIdx.z * ntk;

    // XCD-chunked swizzle: each XCD gets contiguous rb-major chunk (T1/m204).
    const int gx = gridDim.x;
    const int nwg = gx * gridDim.y;
    int flat = blockIdx.y*gx + blockIdx.x;
    flat = (flat & 7)*(nwg >> 3) + (flat >> 3);     // nwg % 8 == 0 always here
    const int cb = flat % gx, rb = flat / gx;

    const char* apan = Ap + ((size_t)rb*ntk_all + kt0)*TA;
    const char* wpan = Wp + ((size_t)cb*ntk_all + kt0)*TB;
    C += (size_t)blockIdx.z * zstride;

    const int lane = tid&63, wid = tid>>6;
    const int wm = wid>>1, wn = wid&1;
    const int fr = lane&15, kh = lane>>4;
    const int shi = (kh ^ (fr&7))<<4;
    int aoff[MWF], boff[4];
#pragma unroll
    for (int mf=0;mf<MWF;mf++) aoff[mf] = (wm*(BM/2)+mf*16+fr)*128 + shi;
#pragma unroll
    for (int nf=0;nf<4;nf++)  boff[nf] = (wn*64+nf*16+fr)*128 + shi;

    f32x4 acc[MWF][4];
#pragma unroll
    for (int i=0;i<MWF;i++)
#pragma unroll
        for (int j=0;j<4;j++) acc[i][j] = (f32x4){0.f,0.f,0.f,0.f};

    auto stage = [&](int buf, int kt){
        const char* as_ = apan + (size_t)kt*TA + tid*16;
        const char* ws_ = wpan + (size_t)kt*TB + tid*16;
        char* ld = lds + buf*BUF + tid*16;
#pragma unroll
        for (int i=0;i<MWF;i++) GLD_LDS16(as_ + i*4096, ld + i*4096);
#pragma unroll
        for (int i=0;i<4;i++)   GLD_LDS16(ws_ + i*4096, ld + TA + i*4096);
    };

    stage(0, 0);
    __syncthreads();
    for (int kt=0; kt<ntk; ++kt){
        const int cur = kt&1;
        if (kt+1 < ntk) stage(cur^1, kt+1);
        const char* Ab = lds + cur*BUF;
        const char* Bb = Ab + TA;
        bf16x8 ah[MWF], al[MWF], bh[4], bl[4];
#pragma unroll
        for (int mf=0;mf<MWF;mf++){
            ah[mf] = *(const bf16x8*)(Ab + aoff[mf]);
            al[mf] = *(const bf16x8*)(Ab + (aoff[mf]^64));
        }
#pragma unroll
        for (int nf=0;nf<4;nf++){
            bh[nf] = *(const bf16x8*)(Bb + boff[nf]);
            bl[nf] = *(const bf16x8*)(Bb + (boff[nf]^64));
        }
#pragma unroll
        for (int mf=0;mf<MWF;mf++)
#pragma unroll
            for (int nf=0;nf<4;nf++){
                acc[mf][nf] = __builtin_amdgcn_mfma_f32_16x16x32_bf16(ah[mf], bh[nf], acc[mf][nf], 0,0,0);
                acc[mf][nf] = __builtin_amdgcn_mfma_f32_16x16x32_bf16(ah[mf], bl[nf], acc[mf][nf], 0,0,0);
                acc[mf][nf] = __builtin_amdgcn_mfma_f32_16x16x32_bf16(al[mf], bh[nf], acc[mf][nf], 0,0,0);
            }
        __syncthreads();
    }

#pragma unroll
    for (int mf=0; mf<MWF; mf++){
        const int grow = rb*BM + wm*(BM/2) + mf*16 + kh*4;
#pragma unroll
        for (int nf=0; nf<4; nf++){
            const int gcol = cb*128 + wn*64 + nf*16 + fr;
            if (gcol < N){
                const float bv = (EPI>=1) ? bias[gcol] : 0.f;
#pragma unroll
                for (int j=0;j<4;j++){
                    float v = acc[mf][nf][j] + bv;
                    if (EPI==2) v = fmaxf(v, 0.f);
                    if (EPI==3) v = fmaxf(v,0.f) + log1pf(__expf(-fabsf(v)));
                    C[(size_t)(grow+j)*ldc + gcol] = v;
                }
            }
        }
    }
}

// ---------------------------------------------------------------------------
// Split-K reduce + epilogue + optional repack.
// PK: 0 fp32 only; 1 packed-only (BMO=64, ntk2=N/32); 2 fp32 + pack cols<32
// (BMO=128). EPI: 0 none, 1 +bias, 2 relu(+bias).
// ---------------------------------------------------------------------------
template<int EPI, int PK, int TAG>
__global__ __launch_bounds__(256)
void redk(const float* __restrict__ part, size_t zs, int nz,
          const float* __restrict__ bias, float* __restrict__ C,
          char* __restrict__ pkout, int N, int nsh, int total4)
{
    const int gid = blockIdx.x*256 + threadIdx.x;
    if (gid >= total4) return;
    const int c = (gid<<2) & (N-1);
    const int r = gid >> (nsh-2);
    const float* p0 = part + (size_t)r*N + c;
    float4 a = *(const float4*)p0;
    for (int z=1; z<nz; z++){
        const float4 b = *(const float4*)(p0 + z*zs);
        a.x+=b.x; a.y+=b.y; a.z+=b.z; a.w+=b.w;
    }
    float v[4] = {a.x, a.y, a.z, a.w};
    if (EPI>=1){
        const float4 bv = *(const float4*)(bias + c);
        v[0]+=bv.x; v[1]+=bv.y; v[2]+=bv.z; v[3]+=bv.w;
    }
    if (EPI==2){
#pragma unroll
        for (int u=0;u<4;u++) v[u] = fmaxf(v[u], 0.f);
    }
    if (PK != 1) *(float4*)(C + (size_t)r*N + c) = make_float4(v[0],v[1],v[2],v[3]);
    if (PK == 1 || (PK == 2 && c < 32)){
        const size_t tb = (PK==1)
            ? ((size_t)(r>>6)*(N>>5) + (c>>5))*8192 + (size_t)(r&63)*128
            : (size_t)(r>>7)*16384 + (size_t)(r&127)*128;
        const int gq = (c>>3)&3, rx = r&7, byt = (c&7)*2;
        ushort4 hh, ll;
        hh.x=hi16(v[0]); hh.y=hi16(v[1]); hh.z=hi16(v[2]); hh.w=hi16(v[3]);
        ll.x=lo16(v[0]); ll.y=lo16(v[1]); ll.z=lo16(v[2]); ll.w=lo16(v[3]);
        *(ushort4*)(pkout + tb + (size_t)(gq^rx)*16 + byt)      = hh;
        *(ushort4*)(pkout + tb + (size_t)((4|gq)^rx)*16 + byt)  = ll;
    }
}

// ---------------------------------------------------------------------------
// Causal depthwise conv1d (k=4) + SiLU -> xi fp32 + packed (BM=64, K=1024).
// ---------------------------------------------------------------------------
__global__ __launch_bounds__(256)
void conv_silu_pack(const float* __restrict__ xz, const float* __restrict__ cw,
                    const float* __restrict__ cb, float* __restrict__ xi,
                    char* __restrict__ xi_pk)
{
    const int tid = threadIdx.x;
    const int j  = tid & 127;
    const int rl = tid >> 7;
    const int row = blockIdx.x*2 + rl;
    const int l = row & (L_SEQ-1);
    const int d0 = j*8;
    float acc[8];
#pragma unroll
    for (int c=0;c<8;c++) acc[c] = cb[d0+c];
    float wt[8][4];
#pragma unroll
    for (int c=0;c<8;c++){
        const float4 w4 = *(const float4*)(cw + (d0+c)*4);
        wt[c][0]=w4.x; wt[c][1]=w4.y; wt[c][2]=w4.z; wt[c][3]=w4.w;
    }
    const float* base = xz + (size_t)row*2048 + d0;
#pragma unroll
    for (int k=0;k<4;k++){
        if (l-3+k >= 0){
            const float* xp = base + (k-3)*2048;
#pragma unroll
            for (int c=0;c<8;c++) acc[c] = fmaf(wt[c][k], xp[c], acc[c]);
        }
    }
    float v[8];
#pragma unroll
    for (int c=0;c<8;c++) v[c] = acc[c] * sigmoidf_(acc[c]);
    *(float4*)(xi + (size_t)row*1024 + d0)     = make_float4(v[0],v[1],v[2],v[3]);
    *(float4*)(xi + (size_t)row*1024 + d0 + 4) = make_float4(v[4],v[5],v[6],v[7]);
    const int g = (d0>>3)&3, kb = d0>>5;
    const size_t tbase = ((size_t)(row>>6)*32 + kb)*8192
                       + ((row&63)>>5)*4096 + (row&31)*128;
    const int s_hi = g ^ (row&7);
    u16x8 h, lo;
#pragma unroll
    for (int c=0;c<8;c++){ h[c] = hi16(v[c]); lo[c] = lo16(v[c]); }
    *(u16x8*)(xi_pk + tbase + s_hi*16)        = h;
    *(u16x8*)(xi_pk + ((tbase + s_hi*16)^64)) = lo;
}

// ---------------------------------------------------------------------------
// Scan
// ---------------------------------------------------------------------------
__global__ __launch_bounds__(256)
void scan_part1(const float* __restrict__ delta, const float* __restrict__ xi,
                const float* __restrict__ dbc, const float* __restrict__ A_log,
                float* __restrict__ Aprod, float* __restrict__ Bsum)
{
    const int d = blockIdx.x*256 + threadIdx.x;
    const int c = blockIdx.y;
    const int b = blockIdx.z;
    __shared__ float Bm[LCH][16];
    const int r0 = b*L_SEQ + c*LCH;
    for (int idx = threadIdx.x; idx < LCH*16; idx += 256){
        const int i = idx >> 4, n = idx & 15;
        Bm[i][n] = dbc[(size_t)(r0+i)*64 + 32 + n];
    }
    __syncthreads();
    float Ad[16];
#pragma unroll
    for (int n=0;n<16;n++) Ad[n] = -__expf(A_log[d*16+n]);
    float ap[16], bs[16];
#pragma unroll
    for (int n=0;n<16;n++){ ap[n]=1.f; bs[n]=0.f; }
    for (int i=0;i<LCH;i++){
        const size_t r = (size_t)(r0 + i);
        const float dl = delta[r*1024 + d];
        const float xv = xi[r*1024 + d];
        const float dx = dl * xv;
#pragma unroll
        for (int n=0;n<16;n++){
            const float da = __expf(dl * Ad[n]);
            bs[n] = fmaf(da, bs[n], dx * Bm[i][n]);
            ap[n] *= da;
        }
    }
    const size_t o = ((size_t)((b*NCH + c)*1024) + d) * 16;
#pragma unroll
    for (int n=0;n<16;n+=4){
        *(float4*)(Aprod + o + n) = make_float4(ap[n],ap[n+1],ap[n+2],ap[n+3]);
        *(float4*)(Bsum  + o + n) = make_float4(bs[n],bs[n+1],bs[n+2],bs[n+3]);
    }
}

// hinit ALIASES Aprod — deliberately NOT __restrict__.
__global__ __launch_bounds__(256)
void scan_part2(const float* Aprod, const float* Bsum, float* hinit)
{
    const int g = blockIdx.x*256 + threadIdx.x;
    const int n = g & 15; const int d = (g>>4) & 1023; const int b = g >> 14;
    float h = 0.f;
    for (int c=0;c<NCH;c++){
        const size_t o = ((size_t)((b*NCH + c)*1024) + d)*16 + n;
        const float a = Aprod[o];
        const float bb = Bsum[o];
        hinit[o] = h;
        h = fmaf(a, h, bb);
    }
}

__global__ __launch_bounds__(256)
void scan_part3(const float* __restrict__ delta, const float* __restrict__ xi,
                const float* __restrict__ dbc, const float* __restrict__ xz,
                const float* __restrict__ A_log, const float* __restrict__ Dp,
                const float* __restrict__ hinit, char* __restrict__ ypk)
{
    const int d = blockIdx.x*256 + threadIdx.x;
    const int c = blockIdx.y;
    const int b = blockIdx.z;
    __shared__ float Bm[LCH][16], Cm[LCH][16];
    const int r0 = b*L_SEQ + c*LCH;
    for (int idx = threadIdx.x; idx < LCH*16; idx += 256){
        const int i = idx >> 4, n = idx & 15;
        const float* rowp = dbc + (size_t)(r0+i)*64;
        Bm[i][n] = rowp[32+n];
        Cm[i][n] = rowp[48+n];
    }
    __syncthreads();
    float Ad[16];
#pragma unroll
    for (int n=0;n<16;n++) Ad[n] = -__expf(A_log[d*16+n]);
    float h[16];
    const size_t ho = ((size_t)((b*NCH + c)*1024) + d)*16;
#pragma unroll
    for (int n=0;n<16;n++) h[n] = hinit[ho+n];
    const float Dd = Dp[d];
    const int gq = (d>>3)&3, c2 = (d&7)*2;
    for (int i=0;i<LCH;i++){
        const int r = r0 + i;
        const float dl = delta[(size_t)r*1024 + d];
        const float xv = xi[(size_t)r*1024 + d];
        const float dx = dl * xv;
        float yv = 0.f;
#pragma unroll
        for (int n=0;n<16;n++){
            const float da = __expf(dl * Ad[n]);
            h[n] = fmaf(da, h[n], dx * Bm[i][n]);
            yv = fmaf(h[n], Cm[i][n], yv);
        }
        yv = fmaf(Dd, xv, yv);
        const float zv = xz[(size_t)r*2048 + 1024 + d];
        yv *= zv * sigmoidf_(zv);
        const size_t tb = ((size_t)(r>>6)*32 + (d>>5))*8192 + (size_t)(r&63)*128;
        const int rx = r&7;
        *(unsigned short*)(ypk + tb + (size_t)((gq^rx))*16 + c2)     = hi16(yv);
        *(unsigned short*)(ypk + tb + (size_t)(((4|gq)^rx))*16 + c2) = lo16(yv);
    }
}

// ---------------------------------------------------------------------------
// out = [addafter +] LN( a(flip?) + res ) * w + b; optional BM=128 packed out.
// ---------------------------------------------------------------------------
__global__ __launch_bounds__(128)
void ln_k(const float* __restrict__ a, int flipA, const float* __restrict__ res,
          const float* __restrict__ w, const float* __restrict__ bb,
          const float* __restrict__ addafter, float* __restrict__ out,
          char* __restrict__ pk)
{
    const int row = blockIdx.x;
    const int tid = threadIdx.x;
    int ar = row;
    if (flipA) ar = (row & ~(L_SEQ-1)) | ((L_SEQ-1) - (row & (L_SEQ-1)));
    const int col = tid*4;
    const float4 av = *(const float4*)(a + (size_t)ar*512 + col);
    const float4 rv = *(const float4*)(res + (size_t)row*512 + col);
    const float v0=av.x+rv.x, v1=av.y+rv.y, v2=av.z+rv.z, v3=av.w+rv.w;
    float s  = v0+v1+v2+v3;
    float sq = v0*v0+v1*v1+v2*v2+v3*v3;
#pragma unroll
    for (int off=32; off>0; off>>=1){
        s  += __shfl_xor(s, off);
        sq += __shfl_xor(sq, off);
    }
    __shared__ float red[4];
    if ((tid & 63) == 0){ red[(tid>>6)*2] = s; red[(tid>>6)*2+1] = sq; }
    __syncthreads();
    s = red[0] + red[2]; sq = red[1] + red[3];
    const float mean = s * (1.f/512.f);
    const float var  = sq * (1.f/512.f) - mean*mean;
    const float rstd = rsqrtf(var + 1e-5f);
    const float4 wv = *(const float4*)(w + col);
    const float4 bv = *(const float4*)(bb + col);
    float o0 = (v0-mean)*rstd*wv.x + bv.x;
    float o1 = (v1-mean)*rstd*wv.y + bv.y;
    float o2 = (v2-mean)*rstd*wv.z + bv.z;
    float o3 = (v3-mean)*rstd*wv.w + bv.w;
    if (pk){
        const int g = (col>>3)&3, kb = col>>5, h = (col>>2)&1;
        const size_t tbase = ((size_t)(row>>7)*16 + kb)*16384
                           + ((row&127)>>5)*4096 + (row&31)*128;
        const int s_hi = g ^ (row&7);
        ushort4 hh, ll;
        hh.x=hi16(o0); hh.y=hi16(o1); hh.z=hi16(o2); hh.w=hi16(o3);
        ll.x=lo16(o0); ll.y=lo16(o1); ll.z=lo16(o2); ll.w=lo16(o3);
        *(ushort4*)(pk + tbase + s_hi*16 + h*8)        = hh;
        *(ushort4*)(pk + ((tbase + s_hi*16)^64) + h*8) = ll;
    }
    if (addafter){
        const float4 xv = *(const float4*)(addafter + (size_t)row*512 + col);
        o0 += xv.x; o1 += xv.y; o2 += xv.z; o3 += xv.w;
    }
    *(float4*)(out + (size_t)row*512 + col) = make_float4(o0,o1,o2,o3);
}

// ---------------------------------------------------------------------------
extern "C" void kernel_launch(void* const* d_in, const int* in_sizes, int n_in,
                              void* d_out, int out_size, void* d_ws, size_t ws_size,
                              hipStream_t stream)
{
    const float* x = (const float*)d_in[0];
    struct DirP { const float *in_w,*conv_w,*conv_b,*xproj_w,*dt_w,*dt_b,*A_log,*D,*out_w; };
    DirP dp[2];
    for (int p=0;p<2;p++){
        const int b = 1 + p*9;
        dp[p].in_w    = (const float*)d_in[b+0];
        dp[p].conv_w  = (const float*)d_in[b+1];
        dp[p].conv_b  = (const float*)d_in[b+2];
        dp[p].xproj_w = (const float*)d_in[b+3];
        dp[p].dt_w    = (const float*)d_in[b+4];
        dp[p].dt_b    = (const float*)d_in[b+5];
        dp[p].A_log   = (const float*)d_in[b+6];
        dp[p].D       = (const float*)d_in[b+7];
        dp[p].out_w   = (const float*)d_in[b+8];
    }
    const float* lnw[4]; const float* lnb[4];
    for (int i=0;i<4;i++){ lnw[i]=(const float*)d_in[19+2*i]; lnb[i]=(const float*)d_in[20+2*i]; }
    const float* f1w1=(const float*)d_in[27]; const float* f1b1=(const float*)d_in[28];
    const float* f1w2=(const float*)d_in[29]; const float* f1b2=(const float*)d_in[30];
    const float* f2w1=(const float*)d_in[31]; const float* f2b1=(const float*)d_in[32];
    const float* f2w2=(const float*)d_in[33]; const float* f2b2=(const float*)d_in[34];

    // ---- workspace plan: ~199 MiB (ws_size measured 256 MiB via fills) ----
    char* ws = (char*)d_ws;
    size_t off = 0;
    auto alloc = [&](size_t bytes){ char* p = ws + off; off = (off + bytes + 255) & ~(size_t)255; return p; };
    const size_t M = 4096;
    float* xz    = (float*)alloc(M*2048*4);
    float* xi    = (float*)alloc(M*1024*4);
    float* dbc   = (float*)alloc(M*64*4);
    float* delta = (float*)alloc(M*1024*4);
    float* Aprod = (float*)alloc((size_t)2*NCH*1024*16*4);   // hinit aliases
    float* Bsum  = (float*)alloc((size_t)2*NCH*1024*16*4);
    float* mamba = (float*)alloc(M*512*4);                   // also ffo
    float* xf1   = (float*)alloc(M*512*4);                   // also xb1
    float* xf2   = (float*)alloc(M*512*4);
    char*  xpk_f = alloc(M*512*4);                           // also xf1_pk
    char*  xpk_b = alloc(M*512*4);
    char*  apk64 = alloc(M*1024*4);                          // xi_pk / ypk / ffh_pk
    char*  dbc_pk= alloc(M*32*4);
    char*  xf2_pk= alloc(M*512*4);
    float* part  = (float*)alloc(M*1024*4*2);                // split-K slabs (32 MiB)
    unsigned short* w_in[2];  unsigned short* w_xp[2];
    unsigned short* w_dt[2];  unsigned short* w_out[2];
    for (int p=0;p<2;p++){
        w_in[p]  = (unsigned short*)alloc((size_t)262144*16);
        w_xp[p]  = (unsigned short*)alloc((size_t)32768*16);
        w_dt[p]  = (unsigned short*)alloc((size_t)8192*16);
        w_out[p] = (unsigned short*)alloc((size_t)131072*16);
    }
    unsigned short* w_f1w1 = (unsigned short*)alloc((size_t)131072*16);
    unsigned short* w_f1w2 = (unsigned short*)alloc((size_t)131072*16);
    unsigned short* w_f2w1 = (unsigned short*)alloc((size_t)131072*16);
    unsigned short* w_f2w2 = (unsigned short*)alloc((size_t)131072*16);
    float* hinit = Aprod;
    float* ffo   = mamba;
    float* xb1   = xf1;
    char*  xf1_pk= xpk_f;
    (void)ws_size; (void)in_sizes; (void)n_in; (void)out_size;

    const dim3 blk(256);

    // ---- one-launch weight pack + dual x pack ----
    PkTab tab;
    int cur = 0; int ti = 0;
    auto addw = [&](const float* src, unsigned short* dst, int lda, int R, int ksh, int tot){
        tab.d[ti++] = PkD{src, dst, lda, R, ksh, cur}; cur += tot;
    };
    for (int p=0;p<2;p++){
        addw(dp[p].in_w,    w_in[p],  512,  2048, 4, 262144);
        addw(dp[p].xproj_w, w_xp[p],  1024, 64,   5, 32768);
        addw(dp[p].dt_w,    w_dt[p],  32,   1024, 0, 8192);
        addw(dp[p].out_w,   w_out[p], 1024, 512,  5, 131072);
    }
    addw(f1w1, w_f1w1, 512,  1024, 4, 131072);
    addw(f1w2, w_f1w2, 1024, 512,  5, 131072);
    addw(f2w1, w_f2w1, 512,  1024, 4, 131072);
    addw(f2w2, w_f2w2, 1024, 512,  5, 131072);
    tab.total = cur;
    pack_w_all<<<dim3((tab.total+255)/256), blk, 0, stream>>>(tab);
    xpack_both<<<dim3(2048), blk, 0, stream>>>(x, (unsigned short*)xpk_f, (unsigned short*)xpk_b);

    for (int p=0;p<2;p++){
        const DirP& d = dp[p];
        const char* xpk = (p==0) ? xpk_f : xpk_b;
        // in_proj -> xz  (grid 512 = 2 blk/CU)
        pgemm<0,128,0><<<dim3(16,32,1), blk, 0, stream>>>(xpk, (char*)w_in[p], nullptr, xz, 0, 2048, 2048, 512);
        // conv + silu -> xi fp32 + packed
        conv_silu_pack<<<dim3(2048), blk, 0, stream>>>(xz, d.conv_w, d.conv_b, xi, apk64);
        // x_proj: split-K z=4 -> slabs; reduce -> dbc fp32 + dbc_pk
        pgemm<0,64,1><<<dim3(1,64,4), blk, 0, stream>>>(apk64, (char*)w_xp[p], nullptr, part, M*64, 64, 64, 1024);
        redk<0,2,0><<<dim3(256), blk, 0, stream>>>(part, M*64, 4, nullptr, dbc, dbc_pk, 64, 6, 65536);
        // dt_proj + softplus -> delta (z=1, epi in GEMM)
        pgemm<3,128,2><<<dim3(8,32,1), blk, 0, stream>>>(dbc_pk, (char*)w_dt[p], d.dt_b, delta, 0, 1024, 1024, 32);
        // chunked associative scan; part3 writes yb packed directly
        scan_part1<<<dim3(4,NCH,2), blk, 0, stream>>>(delta, xi, dbc, d.A_log, Aprod, Bsum);
        scan_part2<<<dim3(128), blk, 0, stream>>>(Aprod, Bsum, hinit);
        scan_part3<<<dim3(4,NCH,2), blk, 0, stream>>>(delta, xi, dbc, xz, d.A_log, d.D, hinit, apk64);
        // out_proj: split-K z=2 -> slabs; reduce -> mamba
        pgemm<0,64,3><<<dim3(4,64,2), blk, 0, stream>>>(apk64, (char*)w_out[p], nullptr, part, M*512, 512, 512, 1024);
        redk<0,0,1><<<dim3(2048), blk, 0, stream>>>(part, M*512, 2, nullptr, mamba, nullptr, 512, 9, 524288);
        if (p==0){
            ln_k<<<4096,128,0,stream>>>(mamba, 0, x, lnw[0], lnb[0], nullptr, xf1, xf1_pk);
            // ffn1: split-K z=2; reduce applies bias+relu and packs (BMO=64)
            pgemm<0,128,4><<<dim3(8,32,2), blk,0,stream>>>(xf1_pk, (char*)w_f1w1, nullptr, part, M*1024, 1024, 1024, 512);
            redk<2,1,2><<<dim3(4096), blk, 0, stream>>>(part, M*1024, 2, f1b1, nullptr, apk64, 1024, 10, 1048576);
            pgemm<0,64,5><<<dim3(4,64,2), blk,0,stream>>>(apk64, (char*)w_f1w2, nullptr, part, M*512, 512, 512, 1024);
            redk<1,0,3><<<dim3(2048), blk, 0, stream>>>(part, M*512, 2, f1b2, ffo, nullptr, 512, 9, 524288);
            ln_k<<<4096,128,0,stream>>>(ffo, 0, xf1, lnw[1], lnb[1], nullptr, xf2, xf2_pk);
        } else {
            ln_k<<<4096,128,0,stream>>>(mamba, 1, x, lnw[2], lnb[2], nullptr, xb1, nullptr);
            // NOTE: faithful to reference bug — ffn2 consumes x_f2, not x_b
            pgemm<0,128,4><<<dim3(8,32,2), blk,0,stream>>>(xf2_pk, (char*)w_f2w1, nullptr, part, M*1024, 1024, 1024, 512);
            redk<2,1,2><<<dim3(4096), blk, 0, stream>>>(part, M*1024, 2, f2b1, nullptr, apk64, 1024, 10, 1048576);
            pgemm<0,64,5><<<dim3(4,64,2), blk,0,stream>>>(apk64, (char*)w_f2w2, nullptr, part, M*512, 512, 512, 1024);
            redk<1,0,3><<<dim3(2048), blk, 0, stream>>>(part, M*512, 2, f2b2, ffo, nullptr, 512, 9, 524288);
            // x_b2 = LN(ffo + x_b1); final out = x_f2 + x_b2 (fused)
            ln_k<<<4096,128,0,stream>>>(ffo, 0, xb1, lnw[3], lnb[3], xf2, (float*)d_out, nullptr);
        }
    }
}